// Round 6
// baseline (1105.493 us; speedup 1.0000x reference)
//
#include <hip/hip_runtime.h>

#define BB 32
#define SS 256
#define EMBD 256
#define HIDD 512
#define NTAG 45
#define TPAD 48
#define NBLK 32            // worker blocks per direction
#define APAD 520           // 512 + 8 shorts pad -> odd 16B row stride, conflict-free
#define GRID_REC 64        // 2 dirs x 32 blocks, all workers
#define SENT 0x01010101u   // H poison: bf16 0x0101 (~2.4e-38) x2 — unreachable by f2bf(h)

typedef __bf16 bf16x8 __attribute__((ext_vector_type(8)));
typedef float  f32x4  __attribute__((ext_vector_type(4)));
typedef short  s16x8  __attribute__((ext_vector_type(8)));
typedef unsigned u32x4 __attribute__((ext_vector_type(4)));

__device__ __forceinline__ unsigned short f2bf(float x) {
  unsigned u = __builtin_bit_cast(unsigned, x);
  u = (u + 0x7fffu + ((u >> 16) & 1u)) >> 16;  // RNE
  return (unsigned short)u;
}
__device__ __forceinline__ float bf2f(unsigned short u) {
  unsigned v = ((unsigned)u) << 16; return __builtin_bit_cast(float, v);
}

// device-coherent (IF$) store, fire-and-forget — R2/R3-proven semantics
__device__ __forceinline__ void st32_sys(unsigned* p, unsigned v) {
  asm volatile("global_store_dword %0, %1, off sc0 sc1" :: "v"(p), "v"(v) : "memory");
}

#define LD8(CPOL)                                                           \
  asm volatile("global_load_dwordx4 %0, %[q0], off " CPOL "\n\t"            \
               "global_load_dwordx4 %1, %[q1], off " CPOL "\n\t"            \
               "global_load_dwordx4 %2, %[q2], off " CPOL "\n\t"            \
               "global_load_dwordx4 %3, %[q3], off " CPOL "\n\t"            \
               "global_load_dwordx4 %4, %[q4], off " CPOL "\n\t"            \
               "global_load_dwordx4 %5, %[q5], off " CPOL "\n\t"            \
               "global_load_dwordx4 %6, %[q6], off " CPOL "\n\t"            \
               "global_load_dwordx4 %7, %[q7], off " CPOL "\n\t"            \
               "s_waitcnt vmcnt(0)"                                         \
               : "=&v"(v0), "=&v"(v1), "=&v"(v2), "=&v"(v3),                \
                 "=&v"(v4), "=&v"(v5), "=&v"(v6), "=&v"(v7)                 \
               : [q0] "v"(p), [q1] "v"(p + 2048), [q2] "v"(p + 4096),       \
                 [q3] "v"(p + 6144), [q4] "v"(p + 8192), [q5] "v"(p + 10240),\
                 [q6] "v"(p + 12288), [q7] "v"(p + 14336)                   \
               : "memory")

// ---------- pack: embeddings -> bf16 [t][b][e] ----------
__global__ void k_pack_e(const int* __restrict__ x, const float* __restrict__ emb,
                         unsigned short* __restrict__ E) {
  int idx = blockIdx.x * 256 + threadIdx.x;       // exact: S*B*EMB threads
  int e = idx & 255; int bt = idx >> 8; int b = bt & 31; int t = bt >> 5;
  int tok = x[b * SS + t];
  E[idx] = f2bf(emb[(long)tok * EMBD + e]);
}

// ---------- pack weights ----------
// packed row r2 = blk*64 + gate*16 + hl  <->  orig row gate*512 + blk*16 + hl
__global__ void k_pack_w(const float* __restrict__ wih_f, const float* __restrict__ whh_f,
                         const float* __restrict__ bf_,  const float* __restrict__ wih_b,
                         const float* __restrict__ whh_b, const float* __restrict__ bb_,
                         unsigned short* __restrict__ Wh, unsigned short* __restrict__ Wie,
                         float* __restrict__ Bh) {
  long idx = (long)blockIdx.x * 256 + threadIdx.x; // exact: 2*2048*768
  int k = (int)(idx % 768); long rest = idx / 768;
  int r2 = (int)(rest & 2047); int dir = (int)(rest >> 11);
  int blk = r2 >> 6, rl = r2 & 63, gate = rl >> 4, hl = rl & 15;
  int orig = gate * HIDD + blk * 16 + hl;
  const float* wih = dir ? wih_b : wih_f;
  const float* whh = dir ? whh_b : whh_f;
  if (k < HIDD) Wh[((long)(dir * 2048 + r2)) * 512 + k] = f2bf(whh[(long)orig * HIDD + k]);
  else          Wie[((long)(dir * 2048 + r2)) * 256 + (k - 512)] = f2bf(wih[(long)orig * EMBD + (k - 512)]);
  if (k == 0) {
    const float* bias = dir ? bb_ : bf_;
    Bh[dir * 2048 + r2] = bias[orig];
  }
}

// ---------- pack: lin_w -> bf16 [48][1024], lin_b -> [48] ----------
__global__ void k_pack_l(const float* __restrict__ lin_w, const float* __restrict__ lin_b,
                         unsigned short* __restrict__ LW, float* __restrict__ LB) {
  int idx = blockIdx.x * 256 + threadIdx.x;
  if (idx < TPAD * 1024) {
    int tag = idx >> 10; int c = idx & 1023;
    LW[idx] = (tag < NTAG) ? f2bf(lin_w[tag * 1024 + c]) : (unsigned short)0;
  } else if (idx < TPAD * 1024 + TPAD) {
    int tag = idx - TPAD * 1024;
    LB[tag] = (tag < NTAG) ? lin_b[tag] : 0.f;
  }
}

// ---------- input projection: Ep[dir][blk][t][b][row64] = E @ Wie^T + b ----------
__launch_bounds__(256)
__global__ void k_eproj(const unsigned short* __restrict__ E,
                        const unsigned short* __restrict__ Wie,
                        const float* __restrict__ Bh,
                        unsigned short* __restrict__ Ep) {
  __shared__ unsigned short W2[64 * 264];   // 264 = 256+8 pad
  const int bx = blockIdx.x;                // 2*32*64 = 4096
  const int tg = bx & 63, blk = (bx >> 6) & 31, dir = bx >> 11;
  const int tid = threadIdx.x;
  const int w = tid >> 6, lane = tid & 63;
  const int lm = lane & 15, quad = lane >> 4;

  { // stage Wie slice [64][256]
    const unsigned short* src = Wie + ((long)(dir * 2048 + blk * 64)) * 256;
    for (int i = 0; i < 8; ++i) {
      int c = i * 256 + tid;
      int row = c >> 5, off = c & 31;
      *(s16x8*)&W2[row * 264 + off * 8] = *(const s16x8*)&src[row * 256 + off * 8];
    }
  }
  __syncthreads();

  f32x4 acc[2][4] = {};
#pragma unroll
  for (int kk = 0; kk < 8; ++kk) {
    s16x8 av[2];
#pragma unroll
    for (int sub = 0; sub < 2; ++sub)
      av[sub] = *(const s16x8*)&E[((long)(tg * 128 + w * 32 + sub * 16 + lm)) * 256 + kk * 32 + quad * 8];
#pragma unroll
    for (int sub = 0; sub < 2; ++sub)
#pragma unroll
      for (int n = 0; n < 4; ++n) {
        s16x8 bs = *(const s16x8*)&W2[(n * 16 + lm) * 264 + kk * 32 + quad * 8];
        acc[sub][n] = __builtin_amdgcn_mfma_f32_16x16x32_bf16(
            __builtin_bit_cast(bf16x8, av[sub]), __builtin_bit_cast(bf16x8, bs), acc[sub][n], 0, 0, 0);
      }
  }
  float bh[4];
#pragma unroll
  for (int n = 0; n < 4; ++n) bh[n] = Bh[dir * 2048 + blk * 64 + n * 16 + lm];
#pragma unroll
  for (int sub = 0; sub < 2; ++sub)
#pragma unroll
    for (int n = 0; n < 4; ++n)
#pragma unroll
      for (int r = 0; r < 4; ++r) {
        int m = w * 32 + sub * 16 + quad * 4 + r;
        int t = tg * 4 + (m >> 5), b = m & 31;
        int row_l = n * 16 + lm;
        Ep[((((long)(dir * 32 + blk) * 256 + t) * 32 + b) * 64) + row_l] =
            f2bf(acc[sub][n][r] + bh[n]);
      }
}

// ---------- persistent bidirectional LSTM recurrence ----------
// Sentinel protocol, placement-agnostic: H pre-memset to 0x01 bytes; writers
// fire-and-forget sc0sc1 h stores (no drain, no flags); readers LD8 the h
// chunks directly (sc0sc1, IF$) and retry while any dword == SENT. 64 blocks:
// dir = bx&1, blk = bx>>1. Only 2 barriers per step.
__launch_bounds__(256, 1)
__global__ void k_rec(const unsigned short* __restrict__ Wh,
                      const unsigned short* __restrict__ Ep,
                      unsigned short* __restrict__ H) {
  __shared__ unsigned short A_ls[32 * APAD];       // 33280 B: h staging, padded
  __shared__ float G_ls[32 * 66];                  // gates scratch

  const int bx = blockIdx.x;
  const int dir = bx & 1;
  const int blk = bx >> 1;               // 0..31
  const int tid = threadIdx.x;
  const int w = tid >> 6, lane = tid & 63;
  const int lm = lane & 15, quad = lane >> 4;
  const int mt = w >> 1, nt = w & 1;

  // ---- W_hh slice: rows blk*64 + nt*32 + ns*16 + lm ----
  s16x8 wb[2][16];
  {
    const unsigned short* wsrc =
        Wh + ((long)(dir * 2048 + blk * 64 + nt * 32 + lm)) * 512 + quad * 8;
#pragma unroll
    for (int ns = 0; ns < 2; ++ns)
#pragma unroll
      for (int kk = 0; kk < 16; ++kk)
        wb[ns][kk] = *(const s16x8*)&wsrc[ns * 16 * 512 + kk * 32];
  }

  const int gb = tid >> 3, hp = tid & 7;   // gate assembly: (batch, hcol pair)
  float c0s = 0.f, c1s = 0.f;

  unsigned short* Hd = H + (long)dir * SS * BB * HIDD;
  const unsigned short* Epd = Ep + ((long)(dir * 32 + blk) * 256) * 32 * 64;

  for (int t = 0; t < SS; ++t) {
    const int tE = (dir == 0) ? t : (SS - 1 - t);

    // ---- Ep gate pre-activations (independent of h): issue early ----
    unsigned short epv[8];
    {
      const unsigned short* eb =
          Epd + ((long)tE * 32 + (mt * 16 + quad * 4)) * 64 + nt * 32 + lm;
#pragma unroll
      for (int ns = 0; ns < 2; ++ns)
#pragma unroll
        for (int r = 0; r < 4; ++r) epv[ns * 4 + r] = eb[r * 64 + ns * 16];
    }

    f32x4 acc0 = {0.f, 0.f, 0.f, 0.f}, acc1 = {0.f, 0.f, 0.f, 0.f};
    if (t > 0) {
      // ---- poll+stage h[hslot] (32x512 bf16) straight from IF$ ----
      {
        const int hslot = (dir == 0) ? (t - 1) : (SS - t);
        const unsigned short* p = Hd + (long)hslot * BB * HIDD + w * 512 + lane * 8;
        s16x8 v0, v1, v2, v3, v4, v5, v6, v7;
        unsigned bad;
        do {
          LD8("sc0 sc1");
          u32x4 u0 = __builtin_bit_cast(u32x4, v0), u1 = __builtin_bit_cast(u32x4, v1);
          u32x4 u2 = __builtin_bit_cast(u32x4, v2), u3 = __builtin_bit_cast(u32x4, v3);
          u32x4 u4 = __builtin_bit_cast(u32x4, v4), u5 = __builtin_bit_cast(u32x4, v5);
          u32x4 u6 = __builtin_bit_cast(u32x4, v6), u7 = __builtin_bit_cast(u32x4, v7);
          unsigned b0 = (u0.x == SENT) | (u0.y == SENT) | (u0.z == SENT) | (u0.w == SENT);
          unsigned b1 = (u1.x == SENT) | (u1.y == SENT) | (u1.z == SENT) | (u1.w == SENT);
          unsigned b2 = (u2.x == SENT) | (u2.y == SENT) | (u2.z == SENT) | (u2.w == SENT);
          unsigned b3 = (u3.x == SENT) | (u3.y == SENT) | (u3.z == SENT) | (u3.w == SENT);
          unsigned b4 = (u4.x == SENT) | (u4.y == SENT) | (u4.z == SENT) | (u4.w == SENT);
          unsigned b5 = (u5.x == SENT) | (u5.y == SENT) | (u5.z == SENT) | (u5.w == SENT);
          unsigned b6 = (u6.x == SENT) | (u6.y == SENT) | (u6.z == SENT) | (u6.w == SENT);
          unsigned b7 = (u7.x == SENT) | (u7.y == SENT) | (u7.z == SENT) | (u7.w == SENT);
          bad = (b0 | b1) | (b2 | b3) | ((b4 | b5) | (b6 | b7));
        } while (__builtin_expect(bad != 0u, 0));
        unsigned short* d = &A_ls[w * APAD + lane * 8];
        *(s16x8*)(d + 0 * 2080) = v0; *(s16x8*)(d + 1 * 2080) = v1;
        *(s16x8*)(d + 2 * 2080) = v2; *(s16x8*)(d + 3 * 2080) = v3;
        *(s16x8*)(d + 4 * 2080) = v4; *(s16x8*)(d + 5 * 2080) = v5;
        *(s16x8*)(d + 6 * 2080) = v6; *(s16x8*)(d + 7 * 2080) = v7;
      }
      __syncthreads();   // barrier 1: A_ls staged
      // ---- h @ W_hh^T : K=512 ----
#pragma unroll
      for (int kk = 0; kk < 16; ++kk) {
        s16x8 av = *(const s16x8*)&A_ls[(mt * 16 + lm) * APAD + kk * 32 + quad * 8];
        acc0 = __builtin_amdgcn_mfma_f32_16x16x32_bf16(
            __builtin_bit_cast(bf16x8, av), __builtin_bit_cast(bf16x8, wb[0][kk]), acc0, 0, 0, 0);
        acc1 = __builtin_amdgcn_mfma_f32_16x16x32_bf16(
            __builtin_bit_cast(bf16x8, av), __builtin_bit_cast(bf16x8, wb[1][kk]), acc1, 0, 0, 0);
      }
    }
    // ---- gates = acc + Ep -> LDS ----
#pragma unroll
    for (int r = 0; r < 4; ++r) {
      int mm = mt * 16 + quad * 4 + r;     // C/D: row=(lane>>4)*4+reg, col=lane&15
      G_ls[mm * 66 + nt * 32 + lm]      = acc0[r] + bf2f(epv[r]);
      G_ls[mm * 66 + nt * 32 + 16 + lm] = acc1[r] + bf2f(epv[4 + r]);
    }
    __syncthreads();   // barrier 2: gates complete
    // ---- activation: thread -> (batch gb, hcols 2hp, 2hp+1); fire-and-forget store ----
    {
      float gi0 = G_ls[gb * 66 + 0  + 2 * hp], gi1 = G_ls[gb * 66 + 0  + 2 * hp + 1];
      float gf0 = G_ls[gb * 66 + 16 + 2 * hp], gf1 = G_ls[gb * 66 + 16 + 2 * hp + 1];
      float gg0 = G_ls[gb * 66 + 32 + 2 * hp], gg1 = G_ls[gb * 66 + 32 + 2 * hp + 1];
      float go0 = G_ls[gb * 66 + 48 + 2 * hp], go1 = G_ls[gb * 66 + 48 + 2 * hp + 1];
      float si0 = 1.f / (1.f + __expf(-gi0)), si1 = 1.f / (1.f + __expf(-gi1));
      float sf0 = 1.f / (1.f + __expf(-gf0)), sf1 = 1.f / (1.f + __expf(-gf1));
      float so0 = 1.f / (1.f + __expf(-go0)), so1 = 1.f / (1.f + __expf(-go1));
      float tg0 = tanhf(gg0), tg1 = tanhf(gg1);
      c0s = sf0 * c0s + si0 * tg0;
      c1s = sf1 * c1s + si1 * tg1;
      float h0 = so0 * tanhf(c0s), h1 = so1 * tanhf(c1s);
      int tslot = (dir == 0) ? t : (SS - 1 - t);
      unsigned hv = (unsigned)f2bf(h0) | ((unsigned)f2bf(h1) << 16);
      st32_sys((unsigned*)&Hd[(long)tslot * BB * HIDD + (long)gb * HIDD + blk * 16 + 2 * hp], hv);
    }
    // no barrier 3 needed: next G_ls write is after barrier 1 of next iter;
    // next A_ls write only touches this wave's own rows after its own reads.
  }
}

// ---------- emissions: [8192,1024] x [1024,48] bf16 MFMA ----------
__launch_bounds__(256)
__global__ void k_emis(const unsigned short* __restrict__ H,
                       const unsigned short* __restrict__ LW,
                       const float* __restrict__ LB,
                       float* __restrict__ EM) {
  const int row0 = blockIdx.x * 32;
  const int tid = threadIdx.x;
  const int w = tid >> 6, lane = tid & 63;
  const int lm = lane & 15, quad = lane >> 4;
  const unsigned short* Hf = H;
  const unsigned short* Hb = H + (long)SS * BB * HIDD;

  for (int tile = w; tile < 6; tile += 4) {   // M2 x N3 tiles
    int mt = tile / 3, nt = tile % 3;
    int arow = row0 + mt * 16 + lm;
    int nrow = nt * 16 + lm;
    f32x4 acc = {0.f, 0.f, 0.f, 0.f};
#pragma unroll 4
    for (int kk = 0; kk < 32; ++kk) {
      int k0 = kk * 32 + quad * 8;
      s16x8 asv = (k0 < HIDD) ? *(const s16x8*)&Hf[(long)arow * HIDD + k0]
                              : *(const s16x8*)&Hb[(long)arow * HIDD + (k0 - HIDD)];
      s16x8 bsv = *(const s16x8*)&LW[nrow * 1024 + k0];
      acc = __builtin_amdgcn_mfma_f32_16x16x32_bf16(
          __builtin_bit_cast(bf16x8, asv), __builtin_bit_cast(bf16x8, bsv), acc, 0, 0, 0);
    }
    float bias = LB[nrow];
#pragma unroll
    for (int r = 0; r < 4; ++r) {
      int mm = row0 + mt * 16 + quad * 4 + r;
      EM[(long)mm * TPAD + nrow] = acc[r] + bias;
    }
  }
}

// ---------- CRF: one wave per chain, scaled (linear-space) forward ----------
__global__ void k_crf(const int* __restrict__ tags, const float* __restrict__ start_t,
                      const float* __restrict__ end_t, const float* __restrict__ trans,
                      const float* __restrict__ EM, float* __restrict__ chain) {
  __shared__ float T_ls[NTAG * TPAD];
  __shared__ float ET[48 * 48 + 16];
  __shared__ float P_ls[64];
  const int b = blockIdx.x;
  const int lane = threadIdx.x;   // 64 threads, single wave
  const int j = lane;

  for (int i = lane; i < NTAG * NTAG; i += 64)
    T_ls[(i / NTAG) * TPAD + (i % NTAG)] = trans[i];
  for (int i = lane; i < 48 * 48 + 16; i += 64) ET[i] = 0.f;
  __syncthreads();

  float Mj = -1e30f;
  if (j < NTAG) {
    for (int i = 0; i < NTAG; ++i) Mj = fmaxf(Mj, T_ls[i * TPAD + j]);
    for (int i = 0; i < NTAG; ++i) ET[i * 48 + j] = __expf(T_ls[i * TPAD + j] - Mj);
  }
  __syncthreads();

  float et[48];
#pragma unroll
  for (int i = 0; i < 48; ++i) et[i] = ET[i * 48 + j];

  float part = 0.f;
  for (int t = lane; t < SS; t += 64) {
    int tg = tags[b * SS + t];
    part += EM[((long)t * BB + b) * TPAD + tg];
    if (t + 1 < SS) part += T_ls[tg * TPAD + tags[b * SS + t + 1]];
    if (t == 0)      part += start_t[tg];
    if (t == SS - 1) part += end_t[tg];
  }
  for (int off = 32; off; off >>= 1) part += __shfl_down(part, off);
  float score = __shfl(part, 0);

  float alpha = (j < NTAG) ? (start_t[j] + EM[(long)b * TPAD + j]) : -1e30f;
  float e_next = (j < NTAG) ? EM[((long)BB + b) * TPAD + j] : 0.f;
  for (int t = 1; t < SS; ++t) {
    float e_cur = e_next;
    if (t < SS - 1) e_next = (j < NTAG) ? EM[((long)(t + 1) * BB + b) * TPAD + j] : 0.f;
    float am = alpha;
#pragma unroll
    for (int off = 32; off; off >>= 1) am = fmaxf(am, __shfl_xor(am, off));
    float p = __expf(alpha - am);
    P_ls[lane] = p;
    __builtin_amdgcn_wave_barrier();
    float s0 = 0.f, s1 = 0.f, s2 = 0.f, s3 = 0.f;
#pragma unroll
    for (int i0 = 0; i0 < 48; i0 += 4) {
      f32x4 pv = *(const f32x4*)&P_ls[i0];
      s0 += pv.x * et[i0];
      s1 += pv.y * et[i0 + 1];
      s2 += pv.z * et[i0 + 2];
      s3 += pv.w * et[i0 + 3];
    }
    __builtin_amdgcn_wave_barrier();
    float s = (s0 + s1) + (s2 + s3);
    float na = am + Mj + __logf(s) + e_cur;
    alpha = (j < NTAG) ? na : -1e30f;
  }
  float v = (j < NTAG) ? (alpha + end_t[j]) : -1e30f;
  float mx = v;
  for (int off = 32; off; off >>= 1) mx = fmaxf(mx, __shfl_xor(mx, off));
  float s = __expf(v - mx);
  for (int off = 32; off; off >>= 1) s += __shfl_xor(s, off);
  if (lane == 0) chain[b] = score - (mx + __logf(s));
}

__global__ void k_fin(const float* __restrict__ chain, float* __restrict__ out) {
  int lane = threadIdx.x;
  float v = (lane < BB) ? chain[lane] : 0.f;
  for (int off = 32; off; off >>= 1) v += __shfl_xor(v, off);
  if (lane == 0) out[0] = -v / (float)BB;
}

extern "C" void kernel_launch(void* const* d_in, const int* in_sizes, int n_in,
                              void* d_out, int out_size, void* d_ws, size_t ws_size,
                              hipStream_t stream) {
  const int*   x      = (const int*)d_in[0];
  const int*   tags   = (const int*)d_in[1];
  const float* emb    = (const float*)d_in[2];
  const float* wih_f  = (const float*)d_in[3];
  const float* whh_f  = (const float*)d_in[4];
  const float* b_f    = (const float*)d_in[5];
  const float* wih_b  = (const float*)d_in[6];
  const float* whh_b  = (const float*)d_in[7];
  const float* b_b    = (const float*)d_in[8];
  const float* lin_w  = (const float*)d_in[9];
  const float* lin_b  = (const float*)d_in[10];
  const float* start_t= (const float*)d_in[11];
  const float* end_t  = (const float*)d_in[12];
  const float* trans  = (const float*)d_in[13];

  char* ws = (char*)d_ws;
  size_t off = 0;
  auto alloc = [&](size_t bytes) {
    void* p = ws + off; off = (off + bytes + 255) & ~(size_t)255; return p;
  };
  unsigned short* E   = (unsigned short*)alloc((size_t)SS * BB * EMBD * 2);      // 4 MB
  unsigned short* Wh  = (unsigned short*)alloc((size_t)2 * 2048 * 512 * 2);      // 4 MB
  unsigned short* Wie = (unsigned short*)alloc((size_t)2 * 2048 * 256 * 2);      // 2 MB
  float*          Bh  = (float*)         alloc((size_t)2 * 2048 * 4);
  unsigned short* Ep  = (unsigned short*)alloc((size_t)2 * 32 * 256 * 32 * 64 * 2); // 67 MB
  unsigned short* H   = (unsigned short*)alloc((size_t)2 * SS * BB * HIDD * 2);  // 16 MB
  unsigned short* LW  = (unsigned short*)alloc((size_t)TPAD * 1024 * 2);
  float*          LB  = (float*)         alloc((size_t)TPAD * 4);
  float*          EM  = (float*)         alloc((size_t)SS * BB * TPAD * 4);      // 1.5 MB
  float*          chain = (float*)       alloc((size_t)BB * 4);

  // H poison: every dword becomes SENT (0x01010101) — the reader poll target.
  hipMemsetAsync(H, 0x01, (size_t)2 * SS * BB * HIDD * 2, stream);
  k_pack_e<<<dim3((SS * BB * EMBD) / 256), dim3(256), 0, stream>>>(x, emb, E);
  k_pack_w<<<dim3((2 * 2048 * 768) / 256), dim3(256), 0, stream>>>(
      wih_f, whh_f, b_f, wih_b, whh_b, b_b, Wh, Wie, Bh);
  k_pack_l<<<dim3((TPAD * 1024 + TPAD + 255) / 256), dim3(256), 0, stream>>>(
      lin_w, lin_b, LW, LB);
  k_eproj<<<dim3(4096), dim3(256), 0, stream>>>(E, Wie, Bh, Ep);

  void* kargs[] = {&Wh, &Ep, &H};
  hipLaunchCooperativeKernel((const void*)k_rec, dim3(GRID_REC), dim3(256), kargs, 0, stream);

  k_emis<<<dim3((SS * BB) / 32), dim3(256), 0, stream>>>(H, LW, LB, EM);
  k_crf<<<dim3(BB), dim3(64), 0, stream>>>(tags, start_t, end_t, trans, EM, chain);
  k_fin<<<dim3(1), dim3(64), 0, stream>>>(chain, (float*)d_out);
}

// Round 7
// 1083.481 us; speedup vs baseline: 1.0203x; 1.0203x over previous
//
#include <hip/hip_runtime.h>

#define BB 32
#define SS 256
#define EMBD 256
#define HIDD 512
#define NTAG 45
#define TPAD 48
#define NBLK 16            // worker blocks per direction (32 hcols each)
#define APAD 520           // 512 + 8 shorts pad -> odd 16B row stride, conflict-free
#define GRID_REC 32        // 2 dirs x 16 blocks
#define GSTR 130           // G_ls row stride (floats)
#define SENT 0x01010101u   // H poison: bf16 0x0101 (~2.4e-38) x2 — unreachable by f2bf(h)

typedef __bf16 bf16x8 __attribute__((ext_vector_type(8)));
typedef float  f32x4  __attribute__((ext_vector_type(4)));
typedef short  s16x8  __attribute__((ext_vector_type(8)));
typedef unsigned u32x4 __attribute__((ext_vector_type(4)));

__device__ __forceinline__ unsigned short f2bf(float x) {
  unsigned u = __builtin_bit_cast(unsigned, x);
  u = (u + 0x7fffu + ((u >> 16) & 1u)) >> 16;  // RNE
  return (unsigned short)u;
}
__device__ __forceinline__ float bf2f(unsigned short u) {
  unsigned v = ((unsigned)u) << 16; return __builtin_bit_cast(float, v);
}
// fast sigmoid/tanh on v_exp_f32 (2^x) + v_rcp_f32 — no libm
__device__ __forceinline__ float fsig(float x) {
  float e = __builtin_amdgcn_exp2f(-1.44269504f * x);
  return __builtin_amdgcn_rcpf(1.f + e);
}
__device__ __forceinline__ float ftanh(float x) {
  float e = __builtin_amdgcn_exp2f(-2.88539008f * x);
  return 2.f * __builtin_amdgcn_rcpf(1.f + e) - 1.f;
}

// device-coherent (IF$) stores, fire-and-forget — R2/R3/R6-proven semantics
__device__ __forceinline__ void st64_sys(unsigned* p, unsigned a, unsigned b) {
  unsigned long long v = ((unsigned long long)b << 32) | (unsigned long long)a;
  asm volatile("global_store_dwordx2 %0, %1, off sc0 sc1" :: "v"(p), "v"(v) : "memory");
}

#define LD8(CPOL)                                                           \
  asm volatile("global_load_dwordx4 %0, %[q0], off " CPOL "\n\t"            \
               "global_load_dwordx4 %1, %[q1], off " CPOL "\n\t"            \
               "global_load_dwordx4 %2, %[q2], off " CPOL "\n\t"            \
               "global_load_dwordx4 %3, %[q3], off " CPOL "\n\t"            \
               "global_load_dwordx4 %4, %[q4], off " CPOL "\n\t"            \
               "global_load_dwordx4 %5, %[q5], off " CPOL "\n\t"            \
               "global_load_dwordx4 %6, %[q6], off " CPOL "\n\t"            \
               "global_load_dwordx4 %7, %[q7], off " CPOL "\n\t"            \
               "s_waitcnt vmcnt(0)"                                         \
               : "=&v"(v0), "=&v"(v1), "=&v"(v2), "=&v"(v3),                \
                 "=&v"(v4), "=&v"(v5), "=&v"(v6), "=&v"(v7)                 \
               : [q0] "v"(p), [q1] "v"(p + 2048), [q2] "v"(p + 4096),       \
                 [q3] "v"(p + 6144), [q4] "v"(p + 8192), [q5] "v"(p + 10240),\
                 [q6] "v"(p + 12288), [q7] "v"(p + 14336)                   \
               : "memory")

// ---------- pack: embeddings -> bf16 [t][b][e] ----------
__global__ void k_pack_e(const int* __restrict__ x, const float* __restrict__ emb,
                         unsigned short* __restrict__ E) {
  int idx = blockIdx.x * 256 + threadIdx.x;       // exact: S*B*EMB threads
  int e = idx & 255; int bt = idx >> 8; int b = bt & 31; int t = bt >> 5;
  int tok = x[b * SS + t];
  E[idx] = f2bf(emb[(long)tok * EMBD + e]);
}

// ---------- pack weights ----------
// packed row r2 = oblk*64 + gate*16 + hl  <->  orig row gate*512 + oblk*16 + hl
__global__ void k_pack_w(const float* __restrict__ wih_f, const float* __restrict__ whh_f,
                         const float* __restrict__ bf_,  const float* __restrict__ wih_b,
                         const float* __restrict__ whh_b, const float* __restrict__ bb_,
                         unsigned short* __restrict__ Wh, unsigned short* __restrict__ Wie,
                         float* __restrict__ Bh) {
  long idx = (long)blockIdx.x * 256 + threadIdx.x; // exact: 2*2048*768
  int k = (int)(idx % 768); long rest = idx / 768;
  int r2 = (int)(rest & 2047); int dir = (int)(rest >> 11);
  int blk = r2 >> 6, rl = r2 & 63, gate = rl >> 4, hl = rl & 15;
  int orig = gate * HIDD + blk * 16 + hl;
  const float* wih = dir ? wih_b : wih_f;
  const float* whh = dir ? whh_b : whh_f;
  if (k < HIDD) Wh[((long)(dir * 2048 + r2)) * 512 + k] = f2bf(whh[(long)orig * HIDD + k]);
  else          Wie[((long)(dir * 2048 + r2)) * 256 + (k - 512)] = f2bf(wih[(long)orig * EMBD + (k - 512)]);
  if (k == 0) {
    const float* bias = dir ? bb_ : bf_;
    Bh[dir * 2048 + r2] = bias[orig];
  }
}

// ---------- pack: lin_w -> bf16 [48][1024], lin_b -> [48] ----------
__global__ void k_pack_l(const float* __restrict__ lin_w, const float* __restrict__ lin_b,
                         unsigned short* __restrict__ LW, float* __restrict__ LB) {
  int idx = blockIdx.x * 256 + threadIdx.x;
  if (idx < TPAD * 1024) {
    int tag = idx >> 10; int c = idx & 1023;
    LW[idx] = (tag < NTAG) ? f2bf(lin_w[tag * 1024 + c]) : (unsigned short)0;
  } else if (idx < TPAD * 1024 + TPAD) {
    int tag = idx - TPAD * 1024;
    LB[tag] = (tag < NTAG) ? lin_b[tag] : 0.f;
  }
}

// ---------- input projection: Ep[dir][oblk][t][b][row64] = E @ Wie^T + b ----------
__launch_bounds__(256)
__global__ void k_eproj(const unsigned short* __restrict__ E,
                        const unsigned short* __restrict__ Wie,
                        const float* __restrict__ Bh,
                        unsigned short* __restrict__ Ep) {
  __shared__ unsigned short W2[64 * 264];   // 264 = 256+8 pad
  const int bx = blockIdx.x;                // 2*32*64 = 4096
  const int tg = bx & 63, blk = (bx >> 6) & 31, dir = bx >> 11;
  const int tid = threadIdx.x;
  const int w = tid >> 6, lane = tid & 63;
  const int lm = lane & 15, quad = lane >> 4;

  { // stage Wie slice [64][256]
    const unsigned short* src = Wie + ((long)(dir * 2048 + blk * 64)) * 256;
    for (int i = 0; i < 8; ++i) {
      int c = i * 256 + tid;
      int row = c >> 5, off = c & 31;
      *(s16x8*)&W2[row * 264 + off * 8] = *(const s16x8*)&src[row * 256 + off * 8];
    }
  }
  __syncthreads();

  f32x4 acc[2][4] = {};
#pragma unroll
  for (int kk = 0; kk < 8; ++kk) {
    s16x8 av[2];
#pragma unroll
    for (int sub = 0; sub < 2; ++sub)
      av[sub] = *(const s16x8*)&E[((long)(tg * 128 + w * 32 + sub * 16 + lm)) * 256 + kk * 32 + quad * 8];
#pragma unroll
    for (int sub = 0; sub < 2; ++sub)
#pragma unroll
      for (int n = 0; n < 4; ++n) {
        s16x8 bs = *(const s16x8*)&W2[(n * 16 + lm) * 264 + kk * 32 + quad * 8];
        acc[sub][n] = __builtin_amdgcn_mfma_f32_16x16x32_bf16(
            __builtin_bit_cast(bf16x8, av[sub]), __builtin_bit_cast(bf16x8, bs), acc[sub][n], 0, 0, 0);
      }
  }
  float bh[4];
#pragma unroll
  for (int n = 0; n < 4; ++n) bh[n] = Bh[dir * 2048 + blk * 64 + n * 16 + lm];
#pragma unroll
  for (int sub = 0; sub < 2; ++sub)
#pragma unroll
    for (int n = 0; n < 4; ++n)
#pragma unroll
      for (int r = 0; r < 4; ++r) {
        int m = w * 32 + sub * 16 + quad * 4 + r;
        int t = tg * 4 + (m >> 5), b = m & 31;
        int row_l = n * 16 + lm;
        Ep[((((long)(dir * 32 + blk) * 256 + t) * 32 + b) * 64) + row_l] =
            f2bf(acc[sub][n][r] + bh[n]);
      }
}

// ---------- persistent bidirectional LSTM recurrence ----------
// R6 sentinel protocol (proven), 16 blocks/dir x 128 gate-rows (32 hcols):
// halves the producer set in the per-step max() and the poll traffic.
// Fast exp2/rcp activations replace libm tanhf.
__launch_bounds__(256, 1)
__global__ void k_rec(const unsigned short* __restrict__ Wh,
                      const unsigned short* __restrict__ Ep,
                      unsigned short* __restrict__ H) {
  __shared__ unsigned short A_ls[32 * APAD];       // 33280 B: h staging, padded
  __shared__ float G_ls[32 * GSTR];                // 16640 B gates scratch

  const int bx = blockIdx.x;
  const int dir = bx & 1;
  const int blk = bx >> 1;               // 0..15
  const int tid = threadIdx.x;
  const int w = tid >> 6, lane = tid & 63;
  const int lm = lane & 15, quad = lane >> 4;

  // ---- W_hh slice: wave w owns gate-rows blk*128 + w*32 + ns*16 + lm ----
  s16x8 wb[2][16];
  {
    const unsigned short* wsrc =
        Wh + ((long)(dir * 2048 + blk * 128 + w * 32 + lm)) * 512 + quad * 8;
#pragma unroll
    for (int ns = 0; ns < 2; ++ns)
#pragma unroll
      for (int kk = 0; kk < 16; ++kk)
        wb[ns][kk] = *(const s16x8*)&wsrc[ns * 16 * 512 + kk * 32];
  }

  const int m_act = tid >> 3, cg = tid & 7;   // activation: batch, hcol-quad
  float cst[4] = {0.f, 0.f, 0.f, 0.f};

  unsigned short* Hd = H + (long)dir * SS * BB * HIDD;
  // Ep indexed by old 64-row blocks: wave w consumes oblk = 2*blk + (w>>1)
  const unsigned short* Epw =
      Ep + ((long)(dir * 32 + 2 * blk + (w >> 1)) * 256) * 32 * 64;
  const int ep_col = (w & 1) * 32 + lm;

  for (int t = 0; t < SS; ++t) {
    const int tE = (dir == 0) ? t : (SS - 1 - t);

    // ---- Ep gate pre-activations (independent of h): issue early ----
    unsigned short epv[16];
    {
      const unsigned short* eb = Epw + ((long)tE * 32 + quad * 4) * 64 + ep_col;
#pragma unroll
      for (int mt = 0; mt < 2; ++mt)
#pragma unroll
        for (int ns = 0; ns < 2; ++ns)
#pragma unroll
          for (int r = 0; r < 4; ++r)
            epv[mt * 8 + ns * 4 + r] = eb[(mt * 16 + r) * 64 + ns * 16];
    }

    f32x4 acc[2][2] = {};
    if (t > 0) {
      // ---- poll+stage h[hslot] (32x512 bf16) straight from IF$ ----
      {
        const int hslot = (dir == 0) ? (t - 1) : (SS - t);
        const unsigned short* p = Hd + (long)hslot * BB * HIDD + w * 512 + lane * 8;
        s16x8 v0, v1, v2, v3, v4, v5, v6, v7;
        unsigned bad;
        do {
          LD8("sc0 sc1");
          u32x4 u0 = __builtin_bit_cast(u32x4, v0), u1 = __builtin_bit_cast(u32x4, v1);
          u32x4 u2 = __builtin_bit_cast(u32x4, v2), u3 = __builtin_bit_cast(u32x4, v3);
          u32x4 u4 = __builtin_bit_cast(u32x4, v4), u5 = __builtin_bit_cast(u32x4, v5);
          u32x4 u6 = __builtin_bit_cast(u32x4, v6), u7 = __builtin_bit_cast(u32x4, v7);
          unsigned b0 = (u0.x == SENT) | (u0.y == SENT) | (u0.z == SENT) | (u0.w == SENT);
          unsigned b1 = (u1.x == SENT) | (u1.y == SENT) | (u1.z == SENT) | (u1.w == SENT);
          unsigned b2 = (u2.x == SENT) | (u2.y == SENT) | (u2.z == SENT) | (u2.w == SENT);
          unsigned b3 = (u3.x == SENT) | (u3.y == SENT) | (u3.z == SENT) | (u3.w == SENT);
          unsigned b4 = (u4.x == SENT) | (u4.y == SENT) | (u4.z == SENT) | (u4.w == SENT);
          unsigned b5 = (u5.x == SENT) | (u5.y == SENT) | (u5.z == SENT) | (u5.w == SENT);
          unsigned b6 = (u6.x == SENT) | (u6.y == SENT) | (u6.z == SENT) | (u6.w == SENT);
          unsigned b7 = (u7.x == SENT) | (u7.y == SENT) | (u7.z == SENT) | (u7.w == SENT);
          bad = (b0 | b1) | (b2 | b3) | ((b4 | b5) | (b6 | b7));
        } while (__builtin_expect(bad != 0u, 0));
        unsigned short* d = &A_ls[w * APAD + lane * 8];
        *(s16x8*)(d + 0 * 2080) = v0; *(s16x8*)(d + 1 * 2080) = v1;
        *(s16x8*)(d + 2 * 2080) = v2; *(s16x8*)(d + 3 * 2080) = v3;
        *(s16x8*)(d + 4 * 2080) = v4; *(s16x8*)(d + 5 * 2080) = v5;
        *(s16x8*)(d + 6 * 2080) = v6; *(s16x8*)(d + 7 * 2080) = v7;
      }
      __syncthreads();   // barrier 1: A_ls staged
      // ---- h @ W_hh^T : K=512, M2 x N2 per wave ----
#pragma unroll
      for (int kk = 0; kk < 16; ++kk) {
        s16x8 av0 = *(const s16x8*)&A_ls[(lm)      * APAD + kk * 32 + quad * 8];
        s16x8 av1 = *(const s16x8*)&A_ls[(16 + lm) * APAD + kk * 32 + quad * 8];
        acc[0][0] = __builtin_amdgcn_mfma_f32_16x16x32_bf16(
            __builtin_bit_cast(bf16x8, av0), __builtin_bit_cast(bf16x8, wb[0][kk]), acc[0][0], 0, 0, 0);
        acc[0][1] = __builtin_amdgcn_mfma_f32_16x16x32_bf16(
            __builtin_bit_cast(bf16x8, av0), __builtin_bit_cast(bf16x8, wb[1][kk]), acc[0][1], 0, 0, 0);
        acc[1][0] = __builtin_amdgcn_mfma_f32_16x16x32_bf16(
            __builtin_bit_cast(bf16x8, av1), __builtin_bit_cast(bf16x8, wb[0][kk]), acc[1][0], 0, 0, 0);
        acc[1][1] = __builtin_amdgcn_mfma_f32_16x16x32_bf16(
            __builtin_bit_cast(bf16x8, av1), __builtin_bit_cast(bf16x8, wb[1][kk]), acc[1][1], 0, 0, 0);
      }
    }
    // ---- gates = acc + Ep -> LDS ----
#pragma unroll
    for (int mt = 0; mt < 2; ++mt)
#pragma unroll
      for (int ns = 0; ns < 2; ++ns)
#pragma unroll
        for (int r = 0; r < 4; ++r) {
          int mm = mt * 16 + quad * 4 + r;   // C/D: row=(lane>>4)*4+reg, col=lane&15
          G_ls[mm * GSTR + w * 32 + ns * 16 + lm] =
              acc[mt][ns][r] + bf2f(epv[mt * 8 + ns * 4 + r]);
        }
    __syncthreads();   // barrier 2: gates complete
    // ---- activation: thread -> (batch m_act, hcols 4cg..4cg+3) ----
    {
      float hv[4];
#pragma unroll
      for (int j = 0; j < 4; ++j) {
        int c = cg * 4 + j, sub = c >> 4, hl = c & 15;
        const float* gp = &G_ls[m_act * GSTR + sub * 64 + hl];
        float si = fsig(gp[0]);
        float sf = fsig(gp[16]);
        float tg = ftanh(gp[32]);
        float so = fsig(gp[48]);
        cst[j] = sf * cst[j] + si * tg;
        hv[j] = so * ftanh(cst[j]);
      }
      int tslot = (dir == 0) ? t : (SS - 1 - t);
      unsigned d0 = (unsigned)f2bf(hv[0]) | ((unsigned)f2bf(hv[1]) << 16);
      unsigned d1 = (unsigned)f2bf(hv[2]) | ((unsigned)f2bf(hv[3]) << 16);
      st64_sys((unsigned*)&Hd[(long)tslot * BB * HIDD + (long)m_act * HIDD + blk * 32 + cg * 4],
               d0, d1);
    }
    // no barrier 3: next-iter G_ls writes are after barrier 1 (see R6 analysis)
  }
}

// ---------- emissions: [8192,1024] x [1024,48] bf16 MFMA ----------
__launch_bounds__(256)
__global__ void k_emis(const unsigned short* __restrict__ H,
                       const unsigned short* __restrict__ LW,
                       const float* __restrict__ LB,
                       float* __restrict__ EM) {
  const int row0 = blockIdx.x * 32;
  const int tid = threadIdx.x;
  const int w = tid >> 6, lane = tid & 63;
  const int lm = lane & 15, quad = lane >> 4;
  const unsigned short* Hf = H;
  const unsigned short* Hb = H + (long)SS * BB * HIDD;

  for (int tile = w; tile < 6; tile += 4) {   // M2 x N3 tiles
    int mt = tile / 3, nt = tile % 3;
    int arow = row0 + mt * 16 + lm;
    int nrow = nt * 16 + lm;
    f32x4 acc = {0.f, 0.f, 0.f, 0.f};
#pragma unroll 4
    for (int kk = 0; kk < 32; ++kk) {
      int k0 = kk * 32 + quad * 8;
      s16x8 asv = (k0 < HIDD) ? *(const s16x8*)&Hf[(long)arow * HIDD + k0]
                              : *(const s16x8*)&Hb[(long)arow * HIDD + (k0 - HIDD)];
      s16x8 bsv = *(const s16x8*)&LW[nrow * 1024 + k0];
      acc = __builtin_amdgcn_mfma_f32_16x16x32_bf16(
          __builtin_bit_cast(bf16x8, asv), __builtin_bit_cast(bf16x8, bsv), acc, 0, 0, 0);
    }
    float bias = LB[nrow];
#pragma unroll
    for (int r = 0; r < 4; ++r) {
      int mm = row0 + mt * 16 + quad * 4 + r;
      EM[(long)mm * TPAD + nrow] = acc[r] + bias;
    }
  }
}

// ---------- CRF: one wave per chain, scaled (linear-space) forward ----------
__global__ void k_crf(const int* __restrict__ tags, const float* __restrict__ start_t,
                      const float* __restrict__ end_t, const float* __restrict__ trans,
                      const float* __restrict__ EM, float* __restrict__ chain) {
  __shared__ float T_ls[NTAG * TPAD];
  __shared__ float ET[48 * 48 + 16];
  __shared__ float P_ls[64];
  const int b = blockIdx.x;
  const int lane = threadIdx.x;   // 64 threads, single wave
  const int j = lane;

  for (int i = lane; i < NTAG * NTAG; i += 64)
    T_ls[(i / NTAG) * TPAD + (i % NTAG)] = trans[i];
  for (int i = lane; i < 48 * 48 + 16; i += 64) ET[i] = 0.f;
  __syncthreads();

  float Mj = -1e30f;
  if (j < NTAG) {
    for (int i = 0; i < NTAG; ++i) Mj = fmaxf(Mj, T_ls[i * TPAD + j]);
    for (int i = 0; i < NTAG; ++i) ET[i * 48 + j] = __expf(T_ls[i * TPAD + j] - Mj);
  }
  __syncthreads();

  float et[48];
#pragma unroll
  for (int i = 0; i < 48; ++i) et[i] = ET[i * 48 + j];

  float part = 0.f;
  for (int t = lane; t < SS; t += 64) {
    int tg = tags[b * SS + t];
    part += EM[((long)t * BB + b) * TPAD + tg];
    if (t + 1 < SS) part += T_ls[tg * TPAD + tags[b * SS + t + 1]];
    if (t == 0)      part += start_t[tg];
    if (t == SS - 1) part += end_t[tg];
  }
  for (int off = 32; off; off >>= 1) part += __shfl_down(part, off);
  float score = __shfl(part, 0);

  float alpha = (j < NTAG) ? (start_t[j] + EM[(long)b * TPAD + j]) : -1e30f;
  float e_next = (j < NTAG) ? EM[((long)BB + b) * TPAD + j] : 0.f;
  for (int t = 1; t < SS; ++t) {
    float e_cur = e_next;
    if (t < SS - 1) e_next = (j < NTAG) ? EM[((long)(t + 1) * BB + b) * TPAD + j] : 0.f;
    float am = alpha;
#pragma unroll
    for (int off = 32; off; off >>= 1) am = fmaxf(am, __shfl_xor(am, off));
    float p = __expf(alpha - am);
    P_ls[lane] = p;
    __builtin_amdgcn_wave_barrier();
    float s0 = 0.f, s1 = 0.f, s2 = 0.f, s3 = 0.f;
#pragma unroll
    for (int i0 = 0; i0 < 48; i0 += 4) {
      f32x4 pv = *(const f32x4*)&P_ls[i0];
      s0 += pv.x * et[i0];
      s1 += pv.y * et[i0 + 1];
      s2 += pv.z * et[i0 + 2];
      s3 += pv.w * et[i0 + 3];
    }
    __builtin_amdgcn_wave_barrier();
    float s = (s0 + s1) + (s2 + s3);
    float na = am + Mj + __logf(s) + e_cur;
    alpha = (j < NTAG) ? na : -1e30f;
  }
  float v = (j < NTAG) ? (alpha + end_t[j]) : -1e30f;
  float mx = v;
  for (int off = 32; off; off >>= 1) mx = fmaxf(mx, __shfl_xor(mx, off));
  float s = __expf(v - mx);
  for (int off = 32; off; off >>= 1) s += __shfl_xor(s, off);
  if (lane == 0) chain[b] = score - (mx + __logf(s));
}

__global__ void k_fin(const float* __restrict__ chain, float* __restrict__ out) {
  int lane = threadIdx.x;
  float v = (lane < BB) ? chain[lane] : 0.f;
  for (int off = 32; off; off >>= 1) v += __shfl_xor(v, off);
  if (lane == 0) out[0] = -v / (float)BB;
}

extern "C" void kernel_launch(void* const* d_in, const int* in_sizes, int n_in,
                              void* d_out, int out_size, void* d_ws, size_t ws_size,
                              hipStream_t stream) {
  const int*   x      = (const int*)d_in[0];
  const int*   tags   = (const int*)d_in[1];
  const float* emb    = (const float*)d_in[2];
  const float* wih_f  = (const float*)d_in[3];
  const float* whh_f  = (const float*)d_in[4];
  const float* b_f    = (const float*)d_in[5];
  const float* wih_b  = (const float*)d_in[6];
  const float* whh_b  = (const float*)d_in[7];
  const float* b_b    = (const float*)d_in[8];
  const float* lin_w  = (const float*)d_in[9];
  const float* lin_b  = (const float*)d_in[10];
  const float* start_t= (const float*)d_in[11];
  const float* end_t  = (const float*)d_in[12];
  const float* trans  = (const float*)d_in[13];

  char* ws = (char*)d_ws;
  size_t off = 0;
  auto alloc = [&](size_t bytes) {
    void* p = ws + off; off = (off + bytes + 255) & ~(size_t)255; return p;
  };
  unsigned short* E   = (unsigned short*)alloc((size_t)SS * BB * EMBD * 2);      // 4 MB
  unsigned short* Wh  = (unsigned short*)alloc((size_t)2 * 2048 * 512 * 2);      // 4 MB
  unsigned short* Wie = (unsigned short*)alloc((size_t)2 * 2048 * 256 * 2);      // 2 MB
  float*          Bh  = (float*)         alloc((size_t)2 * 2048 * 4);
  unsigned short* Ep  = (unsigned short*)alloc((size_t)2 * 32 * 256 * 32 * 64 * 2); // 67 MB
  unsigned short* H   = (unsigned short*)alloc((size_t)2 * SS * BB * HIDD * 2);  // 16 MB
  unsigned short* LW  = (unsigned short*)alloc((size_t)TPAD * 1024 * 2);
  float*          LB  = (float*)         alloc((size_t)TPAD * 4);
  float*          EM  = (float*)         alloc((size_t)SS * BB * TPAD * 4);      // 1.5 MB
  float*          chain = (float*)       alloc((size_t)BB * 4);

  // H poison: every dword becomes SENT (0x01010101) — the reader poll target.
  hipMemsetAsync(H, 0x01, (size_t)2 * SS * BB * HIDD * 2, stream);
  k_pack_e<<<dim3((SS * BB * EMBD) / 256), dim3(256), 0, stream>>>(x, emb, E);
  k_pack_w<<<dim3((2 * 2048 * 768) / 256), dim3(256), 0, stream>>>(
      wih_f, whh_f, b_f, wih_b, whh_b, b_b, Wh, Wie, Bh);
  k_pack_l<<<dim3((TPAD * 1024 + TPAD + 255) / 256), dim3(256), 0, stream>>>(
      lin_w, lin_b, LW, LB);
  k_eproj<<<dim3(4096), dim3(256), 0, stream>>>(E, Wie, Bh, Ep);

  void* kargs[] = {&Wh, &Ep, &H};
  hipLaunchCooperativeKernel((const void*)k_rec, dim3(GRID_REC), dim3(256), kargs, 0, stream);

  k_emis<<<dim3((SS * BB) / 32), dim3(256), 0, stream>>>(H, LW, LB, EM);
  k_crf<<<dim3(BB), dim3(64), 0, stream>>>(tags, start_t, end_t, trans, EM, chain);
  k_fin<<<dim3(1), dim3(64), 0, stream>>>(chain, (float*)d_out);
}